// Round 8
// baseline (335.498 us; speedup 1.0000x reference)
//
#include <hip/hip_runtime.h>
#include <hip/hip_bf16.h>

typedef __attribute__((ext_vector_type(8))) short short8;
typedef __attribute__((ext_vector_type(4))) short short4v;
typedef __attribute__((ext_vector_type(4))) float floatx4;

__device__ __forceinline__ void gload_lds16(const void* g, void* l) {
  __builtin_amdgcn_global_load_lds(
      (const __attribute__((address_space(1))) void*)g,
      (__attribute__((address_space(3))) void*)l, 16, 0, 0);
}

__device__ __forceinline__ float gelu_exact(float x) {
  return 0.5f * x * (1.0f + erff(x * 0.70710678118654752f));
}

#define BM 128
#define BN 128
#define BK 64

// barrier with counted-vmcnt semantics: prefetch loads must land, compiler
// must not move memory ops across (memory clobber both sides).
#define PIPE_BARRIER()                                   \
  do {                                                   \
    asm volatile("s_waitcnt vmcnt(0)" ::: "memory");     \
    __builtin_amdgcn_s_barrier();                        \
    asm volatile("" ::: "memory");                       \
  } while (0)

// ---------------- big-tile GEMM body, 2-phase pipelined ----------------
// C[M,N] = epilogue(A[M,K] @ B[N,K]^T + bias)   A,B bf16; bias fp32
// STORE_T: C chunked-transposed [b][n>>9][col][n&511] (bf16) via LDS transpose
// OUT_F32: C as float (normal layout)
template<bool GELU_OUT, bool HASBIAS, bool STORE_T, bool OUT_F32>
__device__ __forceinline__
void gemm_body(const __hip_bfloat16* __restrict__ Ag,
               const __hip_bfloat16* __restrict__ Bg,
               const float* __restrict__ bias,
               void* __restrict__ Cg,
               int N, int K,
               long sA, long sB, long sC)
{
  // chunked XCD swizzle: same-A-panel blocks (consecutive flat ids) -> same XCD
  const int gx = gridDim.x, gy = gridDim.y;
  const int total = gx * gy * gridDim.z;   // must be divisible by 8
  const int f = blockIdx.x + gx * (blockIdx.y + gy * blockIdx.z);
  const int l = (f & 7) * (total >> 3) + (f >> 3);
  const int bx = l % gx;
  const int rr = l / gx;
  const int by = rr % gy;
  const int bz = rr / gy;

  const long za = (long)bz;
  const __hip_bfloat16* A = Ag + za * sA;
  const __hip_bfloat16* B = Bg + za * sB;

  // double-buffered: per buf, As (128x64) then Bs (128x64); 64 KB total
  __shared__ __align__(16) __hip_bfloat16 SB[2][BM * BK + BN * BK];

  const int tid  = threadIdx.x;
  const int lane = tid & 63;
  const int wid  = tid >> 6;   // 0..3
  const int wr   = wid >> 1;   // wave row 0..1
  const int wc   = wid & 1;    // wave col 0..1
  const int brow = by * BM;
  const int bcol = bx * BN;

  floatx4 acc[4][4];
#pragma unroll
  for (int i = 0; i < 4; i++)
#pragma unroll
    for (int j = 0; j < 4; j++) acc[i][j] = (floatx4){0.f, 0.f, 0.f, 0.f};

  const int r_lo = lane >> 3;        // row within an 8-row group
  const int c8   = (lane & 7) * 8;   // k-offset (elements)
  const int ksteps = K / BK;

  auto STAGE = [&](int buf, int kt) {
    const int k0 = kt * BK;
#pragma unroll
    for (int r = 0; r < 4; ++r) {
      const int grp = r * 4 + wid;       // 16 groups of 8 rows
      const int row = grp * 8 + r_lo;
      gload_lds16(A + (size_t)(brow + row) * K + k0 + c8,
                  (void*)(&SB[buf][0] + grp * 512 + lane * 8));
      gload_lds16(B + (size_t)(bcol + row) * K + k0 + c8,
                  (void*)(&SB[buf][BM * BK] + grp * 512 + lane * 8));
    }
  };

  STAGE(0, 0);
  PIPE_BARRIER();                      // tile 0 landed (each wave waits own loads; barrier joins)

  for (int kt = 0; kt < ksteps; ++kt) {
    const int cur = kt & 1;
    if (kt + 1 < ksteps) STAGE(cur ^ 1, kt + 1);   // prefetch flies under compute
    const __hip_bfloat16* As = &SB[cur][0];
    const __hip_bfloat16* Bs = &SB[cur][BM * BK];
    __builtin_amdgcn_s_setprio(1);
#pragma unroll
    for (int kk = 0; kk < 2; ++kk) {
      short8 a[4], b[4];
#pragma unroll
      for (int i = 0; i < 4; i++)
        a[i] = *(const short8*)(As + (wr * 64 + i * 16 + (lane & 15)) * BK + kk * 32 + (lane >> 4) * 8);
#pragma unroll
      for (int j = 0; j < 4; j++)
        b[j] = *(const short8*)(Bs + (wc * 64 + j * 16 + (lane & 15)) * BK + kk * 32 + (lane >> 4) * 8);
#pragma unroll
      for (int i = 0; i < 4; i++)
#pragma unroll
        for (int j = 0; j < 4; j++)
          acc[i][j] = __builtin_amdgcn_mfma_f32_16x16x32_bf16(a[i], b[j], acc[i][j], 0, 0, 0);
    }
    __builtin_amdgcn_s_setprio(0);
    if (kt + 1 < ksteps) PIPE_BARRIER();           // next tile ready; cur buf free for t+2
  }

  // epilogue: C/D layout col=lane&15, row=(lane>>4)*4+reg
  if (STORE_T) {
    __syncthreads();   // all waves done reading SB before reuse as transpose buffer
    __hip_bfloat16* tr = &SB[0][0];    // 128 x 136 tile (34.8 KB < 64 KB)
#pragma unroll
    for (int i = 0; i < 4; i++) {
      const int rowL = wr * 64 + i * 16 + (lane >> 4) * 4;
#pragma unroll
      for (int j = 0; j < 4; j++) {
        const int colL = wc * 64 + j * 16 + (lane & 15);
        float bv = HASBIAS ? bias[bcol + colL] : 0.f;
        short4v w;
        __hip_bfloat16* wb = (__hip_bfloat16*)&w;
#pragma unroll
        for (int r = 0; r < 4; r++) {
          float v = acc[i][j][r] + bv;
          if (GELU_OUT) v = gelu_exact(v);
          wb[r] = __float2bfloat16(v);
        }
        *(short4v*)&tr[colL * 136 + rowL] = w;
      }
    }
    __syncthreads();
    // stream contiguous along n: 4 lanes cover one 256B row segment
    const int bb  = brow >> 12;
    const int nc  = (brow & 4095) >> 9;
    const int nlo = brow & 511;            // 128-aligned
#pragma unroll
    for (int p = 0; p < 2; ++p) {
      const int rowt = p * 64 + (tid >> 2);     // output row (= C column)
      const int noff = (tid & 3) * 32;          // 32 elems = 64B per thread
      __hip_bfloat16* out = (__hip_bfloat16*)Cg +
          ((size_t)(bb * 8 + nc) * 512 + bcol + rowt) * 512 + nlo + noff;
#pragma unroll
      for (int q = 0; q < 4; q++)
        *(short8*)(out + q * 8) = *(const short8*)&tr[rowt * 136 + noff + q * 8];
    }
  } else {
#pragma unroll
    for (int i = 0; i < 4; i++) {
      const int row0 = brow + wr * 64 + i * 16 + (lane >> 4) * 4;
#pragma unroll
      for (int j = 0; j < 4; j++) {
        const int col = bcol + wc * 64 + j * 16 + (lane & 15);
        float bv = 0.f;
        if (HASBIAS) bv = bias[col];
#pragma unroll
        for (int r = 0; r < 4; r++) {
          const int row = row0 + r;
          float v = acc[i][j][r] + bv;
          if (GELU_OUT) v = gelu_exact(v);
          if (OUT_F32) {
            ((float*)Cg + za * sC)[(size_t)row * N + col] = v;
          } else {
            ((__hip_bfloat16*)Cg + za * sC)[(size_t)row * N + col] = __float2bfloat16(v);
          }
        }
      }
    }
  }
}

// ---- named instantiations (distinct rocprof rows) ----
__global__ __launch_bounds__(256, 2)
void gemm_h1(const __hip_bfloat16* A, const __hip_bfloat16* B, const float* bias, void* C) {
  gemm_body<true, true, false, false>(A, B, bias, C, 512, 512, 0, 0, 0);
}
__global__ __launch_bounds__(256, 2)
void gemm_w1t(const __hip_bfloat16* A, const __hip_bfloat16* B, const float* bias, void* C) {
  gemm_body<false, true, true, false>(A, B, bias, C, 512, 512, 0, 0, 0);
}
__global__ __launch_bounds__(256, 2)
void gemm_h2(const __hip_bfloat16* A, const __hip_bfloat16* B, const float* bias, void* C) {
  gemm_body<true, true, false, false>(A, B, bias, C, 512, 512, 0, 0, 0);
}
__global__ __launch_bounds__(256, 2)
void gemm_w2(const __hip_bfloat16* A, const __hip_bfloat16* B, const float* bias, void* C) {
  gemm_body<false, true, false, false>(A, B, bias, C, 512, 512, 0, 0, 0);
}
__global__ __launch_bounds__(256, 2)
void gemm_y(const __hip_bfloat16* A, const __hip_bfloat16* B, void* C) {
  gemm_body<false, false, false, true>(A, B, nullptr, C, 512, 512,
                                       4096L * 512, 512L * 512, 4096L * 512);
}

// ---------------- small-tile batched GEMM for P partials ----------------
__global__ __launch_bounds__(256, 4)
void gemm_small_nt(const __hip_bfloat16* __restrict__ Ag,
                   const __hip_bfloat16* __restrict__ Bg,
                   __hip_bfloat16* __restrict__ Cg)
{
  const int f = blockIdx.x + 8 * (blockIdx.y + 8 * blockIdx.z);  // 0..4095
  const int xcd  = f & 7;
  const int rank = f >> 3;            // 0..511
  const int z    = xcd + 8 * (rank >> 6);
  const int t    = rank & 63;
  const int by   = t >> 3;
  const int bx   = t & 7;

  const __hip_bfloat16* A = Ag + (size_t)z * 262144;
  const __hip_bfloat16* B = Bg + (size_t)z * 262144;
  __hip_bfloat16*       C = Cg + (size_t)z * 262144;

  __shared__ __align__(16) __hip_bfloat16 As[2][64 * 64];
  __shared__ __align__(16) __hip_bfloat16 Bs[2][64 * 64];

  const int tid  = threadIdx.x;
  const int lane = tid & 63;
  const int wid  = tid >> 6;
  const int wr2  = wid >> 1;
  const int wc2  = wid & 1;
  const int brow = by * 64;
  const int bcol = bx * 64;

  const int srow = tid >> 3;          // 0..31
  const int sk   = (tid & 7) * 8;

  floatx4 acc[2][2];
#pragma unroll
  for (int i = 0; i < 2; i++)
#pragma unroll
    for (int j = 0; j < 2; j++) acc[i][j] = (floatx4){0.f, 0.f, 0.f, 0.f};

#define STAGE_SMALL(buf, kt)                                                   \
  {                                                                            \
    const int k0 = (kt) * 64;                                                  \
    _Pragma("unroll")                                                          \
    for (int r = 0; r < 2; ++r) {                                              \
      const int row = r * 32 + srow;                                           \
      gload_lds16(A + (size_t)(brow + row) * 512 + k0 + sk,                    \
                  (void*)(&As[buf][0] + r * 2048 + tid * 8));                  \
      gload_lds16(B + (size_t)(bcol + row) * 512 + k0 + sk,                    \
                  (void*)(&Bs[buf][0] + r * 2048 + tid * 8));                  \
    }                                                                          \
  }

  STAGE_SMALL(0, 0);
  PIPE_BARRIER();

  for (int kt = 0; kt < 8; ++kt) {
    const int cur = kt & 1;
    if (kt < 7) STAGE_SMALL(cur ^ 1, kt + 1);
    __builtin_amdgcn_s_setprio(1);
#pragma unroll
    for (int kk = 0; kk < 2; ++kk) {
      short8 a[2], b[2];
#pragma unroll
      for (int i = 0; i < 2; i++)
        a[i] = *(const short8*)(&As[cur][0] + (wr2 * 32 + i * 16 + (lane & 15)) * 64 + kk * 32 + (lane >> 4) * 8);
#pragma unroll
      for (int j = 0; j < 2; j++)
        b[j] = *(const short8*)(&Bs[cur][0] + (wc2 * 32 + j * 16 + (lane & 15)) * 64 + kk * 32 + (lane >> 4) * 8);
#pragma unroll
      for (int i = 0; i < 2; i++)
#pragma unroll
        for (int j = 0; j < 2; j++)
          acc[i][j] = __builtin_amdgcn_mfma_f32_16x16x32_bf16(a[i], b[j], acc[i][j], 0, 0, 0);
    }
    __builtin_amdgcn_s_setprio(0);
    if (kt < 7) PIPE_BARRIER();
  }
#undef STAGE_SMALL

#pragma unroll
  for (int i = 0; i < 2; i++) {
    const int row0 = brow + wr2 * 32 + i * 16 + (lane >> 4) * 4;
#pragma unroll
    for (int j = 0; j < 2; j++) {
      const int col = bcol + wc2 * 32 + j * 16 + (lane & 15);
#pragma unroll
      for (int r = 0; r < 4; r++)
        C[(size_t)(row0 + r) * 512 + col] = __float2bfloat16(acc[i][j][r]);
    }
  }
}

// fp32 -> bf16, 8 elements/thread; n must be divisible by 8
__global__ __launch_bounds__(256)
void cvt_f32_bf16(const float* __restrict__ in, __hip_bfloat16* __restrict__ out, long n) {
  long i = ((long)blockIdx.x * 256 + threadIdx.x) * 8;
  if (i >= n) return;
  float4 v0 = *(const float4*)(in + i);
  float4 v1 = *(const float4*)(in + i + 4);
  short8 o;
  __hip_bfloat16* ob = (__hip_bfloat16*)&o;
  ob[0] = __float2bfloat16(v0.x); ob[1] = __float2bfloat16(v0.y);
  ob[2] = __float2bfloat16(v0.z); ob[3] = __float2bfloat16(v0.w);
  ob[4] = __float2bfloat16(v1.x); ob[5] = __float2bfloat16(v1.y);
  ob[6] = __float2bfloat16(v1.z); ob[7] = __float2bfloat16(v1.w);
  *(short8*)(out + i) = o;
}

// X fp32 [B][4096][512] -> Xb bf16 [B][4096][512]
//                     AND XTc bf16 [B][8 n-chunks][512 d][512 n]
__global__ __launch_bounds__(256)
void cvt_x_xt(const float* __restrict__ X,
              __hip_bfloat16* __restrict__ Xb,
              __hip_bfloat16* __restrict__ XT)
{
  __shared__ __hip_bfloat16 t[64][66];
  const int b  = blockIdx.z;
  const int n0 = blockIdx.y * 64;
  const int d0 = blockIdx.x * 64;
  const float* I = X + (size_t)b * 4096 * 512;
  __hip_bfloat16* XB = Xb + (size_t)b * 4096 * 512;
  __hip_bfloat16* XO = XT + ((size_t)b * 8 + (n0 >> 9)) * 512 * 512;
  const int nl0 = n0 & 511;
  const int tid = threadIdx.x;
#pragma unroll
  for (int it = 0; it < 4; ++it) {
    const int idx = it * 256 + tid;      // 0..1023
    const int r   = idx >> 4;            // n-local 0..63
    const int c4  = (idx & 15) * 4;      // d-local 0..60
    float4 v = *(const float4*)&I[(size_t)(n0 + r) * 512 + d0 + c4];
    short4v o;
    __hip_bfloat16* ob = (__hip_bfloat16*)&o;
    ob[0] = __float2bfloat16(v.x); ob[1] = __float2bfloat16(v.y);
    ob[2] = __float2bfloat16(v.z); ob[3] = __float2bfloat16(v.w);
    t[r][c4]     = ob[0]; t[r][c4 + 1] = ob[1];
    t[r][c4 + 2] = ob[2]; t[r][c4 + 3] = ob[3];
    *(short4v*)&XB[(size_t)(n0 + r) * 512 + d0 + c4] = o;
  }
  __syncthreads();
#pragma unroll
  for (int it = 0; it < 4; ++it) {
    const int idx = it * 256 + tid;
    const int dr  = idx >> 4;            // d-local 0..63
    const int n4  = (idx & 15) * 4;      // n-local 0..60
    short4v o;
    __hip_bfloat16* ob = (__hip_bfloat16*)&o;
#pragma unroll
    for (int j = 0; j < 4; j++) ob[j] = t[n4 + j][dr];
    *(short4v*)&XO[(size_t)(d0 + dr) * 512 + nl0 + n4] = o;
  }
}

// AT[b][i] = bf16(GELU(sum_kc part[(b*8+kc)][i])), i in [0, 512*512)
__global__ __launch_bounds__(256)
void reduce_gelu_bf16(const __hip_bfloat16* __restrict__ part,
                      __hip_bfloat16* __restrict__ AT) {
  const long o = ((long)blockIdx.x * 256 + threadIdx.x) * 8;
  const long b = o >> 18;
  const long i = o & 262143;
  float s[8] = {0.f, 0.f, 0.f, 0.f, 0.f, 0.f, 0.f, 0.f};
#pragma unroll
  for (int kc = 0; kc < 8; kc++) {
    short8 v = *(const short8*)(part + (((b << 3) + kc) << 18) + i);
#pragma unroll
    for (int j = 0; j < 8; j++) s[j] += __bfloat162float(((const __hip_bfloat16*)&v)[j]);
  }
  short8 o8;
#pragma unroll
  for (int j = 0; j < 8; j++)
    ((__hip_bfloat16*)&o8)[j] = __float2bfloat16(gelu_exact(s[j]));
  *(short8*)(AT + o) = o8;
}

extern "C" void kernel_launch(void* const* d_in, const int* in_sizes, int n_in,
                              void* d_out, int out_size, void* d_ws, size_t ws_size,
                              hipStream_t stream) {
  const float* X   = (const float*)d_in[0];
  const float* W1a = (const float*)d_in[1];
  const float* b1a = (const float*)d_in[2];
  const float* W1b = (const float*)d_in[3];
  const float* b1b = (const float*)d_in[4];
  const float* W2a = (const float*)d_in[5];
  const float* b2a = (const float*)d_in[6];
  const float* W2b = (const float*)d_in[7];
  const float* b2b = (const float*)d_in[8];
  float* Y = (float*)d_out;

  char* ws = (char*)d_ws;
  const size_t SZ = 33554432;  // 32768*512*2 bytes
  __hip_bfloat16* Xb   = (__hip_bfloat16*)(ws);                 // [8,4096,512]; later P partials [64][512][512]
  __hip_bfloat16* H    = (__hip_bfloat16*)(ws + SZ);            // [32768,512] (H1, then H2)
  __hip_bfloat16* W1T  = (__hip_bfloat16*)(ws + 2 * SZ);        // [8][8][512][512] chunked; later W2m
  __hip_bfloat16* XT   = (__hip_bfloat16*)(ws + 3 * SZ);        // [8][8][512][512] chunked
  __hip_bfloat16* AT   = (__hip_bfloat16*)(ws + 4 * SZ);        // [8][512][512]
  __hip_bfloat16* Wb   = (__hip_bfloat16*)(ws + 4 * SZ + 4194304); // 4x[512,512] bf16
  __hip_bfloat16* W1ab = Wb;
  __hip_bfloat16* W1bb = Wb + 262144;
  __hip_bfloat16* W2ab = Wb + 2 * 262144;
  __hip_bfloat16* W2bb = Wb + 3 * 262144;

  dim3 blk(256);

  // 0) conversions; X also emits chunked XT (fused transpose)
  cvt_f32_bf16<<<128,  blk, 0, stream>>>(W1a, W1ab, 262144L);
  cvt_f32_bf16<<<128,  blk, 0, stream>>>(W1b, W1bb, 262144L);
  cvt_f32_bf16<<<128,  blk, 0, stream>>>(W2a, W2ab, 262144L);
  cvt_f32_bf16<<<128,  blk, 0, stream>>>(W2b, W2bb, 262144L);
  cvt_x_xt<<<dim3(8, 64, 8), blk, 0, stream>>>(X, Xb, XT);

  // 1) H1 = GELU(Xb @ W1a^T + b1a)            [32768,512] bf16 -> H
  gemm_h1<<<dim3(4, 256, 1), blk, 0, stream>>>(Xb, W1ab, b1a, H);
  // 2) W1Tc[b][nc][p][nl] = H1 @ W1b^T + b1b (chunked-transposed store via LDS)
  gemm_w1t<<<dim3(4, 256, 1), blk, 0, stream>>>(H, W1bb, b1b, W1T);
  // 3) H2 = GELU(Xb @ W2a^T + b2a) -> H (H1 consumed; Xb dead after this)
  gemm_h2<<<dim3(4, 256, 1), blk, 0, stream>>>(Xb, W2ab, b2a, H);
  // 4) P partials: part[z] = XTc[z] @ W1Tc[z]^T (64 batched 512^3, 64x64 tiles)
  __hip_bfloat16* part = Xb;  // reuse (Xb dead)
  gemm_small_nt<<<dim3(8, 8, 64), blk, 0, stream>>>(XT, W1T, part);
  // 5) AT[b][d][p] = GELU(sum_kc part) -> AT
  reduce_gelu_bf16<<<1024, blk, 0, stream>>>(part, AT);
  // 6) W2m = H2 @ W2b^T + b2b -> reuse W1T buffer (W1Tc dead after step 4)
  __hip_bfloat16* W2m = W1T;
  gemm_w2<<<dim3(4, 256, 1), blk, 0, stream>>>(H, W2bb, b2b, W2m);
  // 7) Y = W2m @ AT^T per batch -> fp32 out   [4096,512]
  gemm_y<<<dim3(4, 32, 8), blk, 0, stream>>>(W2m, AT, Y);
}

// Round 9
// 273.497 us; speedup vs baseline: 1.2267x; 1.2267x over previous
//
#include <hip/hip_runtime.h>
#include <hip/hip_bf16.h>

typedef __attribute__((ext_vector_type(8))) short short8;
typedef __attribute__((ext_vector_type(4))) short short4v;
typedef __attribute__((ext_vector_type(4))) float floatx4;

__device__ __forceinline__ void gload_lds16(const void* g, void* l) {
  __builtin_amdgcn_global_load_lds(
      (const __attribute__((address_space(1))) void*)g,
      (__attribute__((address_space(3))) void*)l, 16, 0, 0);
}

// tanh-approx GELU: max |err| vs exact-erf ~3e-3 (fine vs threshold 142)
__device__ __forceinline__ float gelu_fast(float x) {
  float z = 1.5957691216f * (x + 0.044715f * x * x * x);  // 2*0.79788456*(...)
  return x / (1.0f + __expf(-z));
}

#define PIPE_BARRIER()                                   \
  do {                                                   \
    asm volatile("s_waitcnt vmcnt(0)" ::: "memory");     \
    __builtin_amdgcn_s_barrier();                        \
    asm volatile("" ::: "memory");                       \
  } while (0)

// ================= 256x256x(K=512) 2-phase GEMM =================
// C[M,512] = epi(A[M,512] @ B[512,512]^T + bias); 512 thr (8 waves, 2x4),
// per-wave out 128x64, BK=64, dbuf LDS 128KB, T2 swizzle via pre-swizzled
// global source (rule #21: linear LDS dest + XOR'd src + XOR'd ds_read).
// SWZ=1: chunked XCD (grid total must be 256). SWZ=2: P-grid (2,2,64).
template<bool GELU_OUT, bool HASBIAS, bool STORE_T, bool OUT_F32, int SWZ>
__device__ __forceinline__
void gemm256_body(const __hip_bfloat16* __restrict__ Ag,
                  const __hip_bfloat16* __restrict__ Bg,
                  const float* __restrict__ bias,
                  void* __restrict__ Cg,
                  long sA, long sB, long sC)
{
  int bx, by, bz;
  if (SWZ == 1) {
    const int gx = gridDim.x, gy = gridDim.y;
    const int f = blockIdx.x + gx * (blockIdx.y + gy * blockIdx.z);
    const int l = (f & 7) * 32 + (f >> 3);          // total == 256
    bx = l % gx;
    const int rr = l / gx;
    by = rr % gy;
    bz = rr / gy;
  } else {  // SWZ==2: grid (2,2,64); 4 tiles of chunk z co-scheduled on one XCD
    const int f = blockIdx.x + 2 * (blockIdx.y + 2 * blockIdx.z);
    const int x = f & 7, s = f >> 3;
    bz = x + 8 * (s >> 2);
    bx = s & 1;
    by = (s >> 1) & 1;
  }
  const long za = bz;
  const __hip_bfloat16* A = Ag + za * sA;
  const __hip_bfloat16* B = Bg + za * sB;

  __shared__ __align__(16) __hip_bfloat16 SB[2][2 * 256 * 64];  // [buf][As|Bs] 128KB

  const int tid  = threadIdx.x;
  const int lane = tid & 63;
  const int wid  = tid >> 6;   // 0..7
  const int wr   = wid >> 2;   // 0..1 (row half)
  const int wc   = wid & 3;    // 0..3 (col quarter)
  const int brow = by * 256;
  const int bcol = bx * 256;

  floatx4 acc[8][4];
#pragma unroll
  for (int i = 0; i < 8; i++)
#pragma unroll
    for (int j = 0; j < 4; j++) acc[i][j] = (floatx4){0.f, 0.f, 0.f, 0.f};

  // staging: 4 passes x 64 rows; row = r*64 + (tid>>3); linear LDS slot tid&7;
  // pre-swizzled global slot = (tid&7) ^ (row&7)  [row&7 == (tid>>3)&7]
  const int srow  = tid >> 3;                       // 0..63
  const int skoff = (((tid & 7) ^ (srow & 7))) * 8; // element offset in row

  auto STAGE = [&](int buf, int kt) {
    const int k0 = kt * 64;
#pragma unroll
    for (int r = 0; r < 4; ++r) {
      gload_lds16(A + (size_t)(brow + r * 64 + srow) * 512 + k0 + skoff,
                  (void*)(&SB[buf][0] + r * 4096 + tid * 8));
      gload_lds16(B + (size_t)(bcol + r * 64 + srow) * 512 + k0 + skoff,
                  (void*)(&SB[buf][16384] + r * 4096 + tid * 8));
    }
  };

  // read-side swizzled slot (elems): logical kslot = kk*4+(lane>>4), row&7 == lane&7
  const int rs0 = (((lane >> 4)) ^ (lane & 7)) * 8;
  const int rs1 = ((4 + (lane >> 4)) ^ (lane & 7)) * 8;

  STAGE(0, 0);
  PIPE_BARRIER();

  for (int kt = 0; kt < 8; ++kt) {
    const int cur = kt & 1;
    if (kt < 7) STAGE(cur ^ 1, kt + 1);   // issue next tile before compute
    const __hip_bfloat16* As = &SB[cur][0];
    const __hip_bfloat16* Bs = &SB[cur][16384];
    __builtin_amdgcn_s_setprio(1);
#pragma unroll
    for (int kk = 0; kk < 2; ++kk) {
      const int rs = kk ? rs1 : rs0;
      short8 a[8], b[4];
#pragma unroll
      for (int i = 0; i < 8; i++)
        a[i] = *(const short8*)(As + (wr * 128 + i * 16 + (lane & 15)) * 64 + rs);
#pragma unroll
      for (int j = 0; j < 4; j++)
        b[j] = *(const short8*)(Bs + (wc * 64 + j * 16 + (lane & 15)) * 64 + rs);
#pragma unroll
      for (int i = 0; i < 8; i++)
#pragma unroll
        for (int j = 0; j < 4; j++)
          acc[i][j] = __builtin_amdgcn_mfma_f32_16x16x32_bf16(a[i], b[j], acc[i][j], 0, 0, 0);
    }
    __builtin_amdgcn_s_setprio(0);
    if (kt < 7) PIPE_BARRIER();           // next tile landed; cur reusable at t+2
  }

  // epilogue: C/D layout col=lane&15, row=(lane>>4)*4+reg
  if (STORE_T) {
    // chunked-transposed store [b][n>>9][p][n&511] via LDS transpose, 2 n-halves
    __syncthreads();                       // all waves done with SB
    __hip_bfloat16* tr = &SB[0][0];        // [256 p][132 n-half] = 67.6KB
    const int bb  = brow >> 12;
    const int nc  = (brow & 4095) >> 9;
    const int nlo = brow & 511;            // 0 or 256
#pragma unroll
    for (int h = 0; h < 2; ++h) {
      if (wr == h) {
#pragma unroll
        for (int i = 0; i < 8; i++) {
          const int nl = i * 16 + (lane >> 4) * 4;   // 0..124 within half
#pragma unroll
          for (int j = 0; j < 4; j++) {
            const int col = wc * 64 + j * 16 + (lane & 15);
            const float bv = HASBIAS ? bias[bcol + col] : 0.f;
            short4v w;
            __hip_bfloat16* wb = (__hip_bfloat16*)&w;
#pragma unroll
            for (int r = 0; r < 4; r++) {
              float v = acc[i][j][r] + bv;
              if (GELU_OUT) v = gelu_fast(v);
              wb[r] = __float2bfloat16(v);
            }
            *(short4v*)&tr[col * 132 + nl] = w;
          }
        }
      }
      __syncthreads();
      const int p   = tid >> 1;
      const int seg = (tid & 1) * 64;
      __hip_bfloat16* outp = (__hip_bfloat16*)Cg +
          ((size_t)(bb * 8 + nc) * 512 + bcol + p) * 512 + nlo + h * 128 + seg;
#pragma unroll
      for (int q = 0; q < 8; q++)
        *(short8*)(outp + q * 8) = *(const short8*)&tr[p * 132 + seg + q * 8];
      __syncthreads();
    }
  } else {
#pragma unroll
    for (int i = 0; i < 8; i++) {
      const int row0 = brow + wr * 128 + i * 16 + (lane >> 4) * 4;
#pragma unroll
      for (int j = 0; j < 4; j++) {
        const int col = bcol + wc * 64 + j * 16 + (lane & 15);
        const float bv = HASBIAS ? bias[col] : 0.f;
#pragma unroll
        for (int r = 0; r < 4; r++) {
          float v = acc[i][j][r] + bv;
          if (GELU_OUT) v = gelu_fast(v);
          if (OUT_F32)
            ((float*)Cg + za * sC)[(size_t)(row0 + r) * 512 + col] = v;
          else
            ((__hip_bfloat16*)Cg + za * sC)[(size_t)(row0 + r) * 512 + col] = __float2bfloat16(v);
        }
      }
    }
  }
}

// ---- named instantiations ----
__global__ __launch_bounds__(512, 2)
void g256_h1(const __hip_bfloat16* A, const __hip_bfloat16* B, const float* bias, void* C) {
  gemm256_body<true, true, false, false, 1>(A, B, bias, C, 0, 0, 0);
}
__global__ __launch_bounds__(512, 2)
void g256_w1t(const __hip_bfloat16* A, const __hip_bfloat16* B, const float* bias, void* C) {
  gemm256_body<false, true, true, false, 1>(A, B, bias, C, 0, 0, 0);
}
__global__ __launch_bounds__(512, 2)
void g256_h2(const __hip_bfloat16* A, const __hip_bfloat16* B, const float* bias, void* C) {
  gemm256_body<true, true, false, false, 1>(A, B, bias, C, 0, 0, 0);
}
__global__ __launch_bounds__(512, 2)
void g256_w2(const __hip_bfloat16* A, const __hip_bfloat16* B, const float* bias, void* C) {
  gemm256_body<false, true, false, false, 1>(A, B, bias, C, 0, 0, 0);
}
__global__ __launch_bounds__(512, 2)
void g256_p(const __hip_bfloat16* A, const __hip_bfloat16* B, void* C) {
  gemm256_body<false, false, false, false, 2>(A, B, nullptr, C, 262144, 262144, 262144);
}
__global__ __launch_bounds__(512, 2)
void g256_y(const __hip_bfloat16* A, const __hip_bfloat16* B, void* C) {
  gemm256_body<false, false, false, true, 1>(A, B, nullptr, C,
                                             4096L * 512, 262144, 4096L * 512);
}

// fp32 -> bf16, 8 elements/thread
__global__ __launch_bounds__(256)
void cvt_f32_bf16(const float* __restrict__ in, __hip_bfloat16* __restrict__ out, long n) {
  long i = ((long)blockIdx.x * 256 + threadIdx.x) * 8;
  if (i >= n) return;
  float4 v0 = *(const float4*)(in + i);
  float4 v1 = *(const float4*)(in + i + 4);
  short8 o;
  __hip_bfloat16* ob = (__hip_bfloat16*)&o;
  ob[0] = __float2bfloat16(v0.x); ob[1] = __float2bfloat16(v0.y);
  ob[2] = __float2bfloat16(v0.z); ob[3] = __float2bfloat16(v0.w);
  ob[4] = __float2bfloat16(v1.x); ob[5] = __float2bfloat16(v1.y);
  ob[6] = __float2bfloat16(v1.z); ob[7] = __float2bfloat16(v1.w);
  *(short8*)(out + i) = o;
}

// X fp32 [B][4096][512] -> Xb bf16 + XTc bf16 [B][8][512][512]
__global__ __launch_bounds__(256)
void cvt_x_xt(const float* __restrict__ X,
              __hip_bfloat16* __restrict__ Xb,
              __hip_bfloat16* __restrict__ XT)
{
  __shared__ __hip_bfloat16 t[64][66];
  const int b  = blockIdx.z;
  const int n0 = blockIdx.y * 64;
  const int d0 = blockIdx.x * 64;
  const float* I = X + (size_t)b * 4096 * 512;
  __hip_bfloat16* XB = Xb + (size_t)b * 4096 * 512;
  __hip_bfloat16* XO = XT + ((size_t)b * 8 + (n0 >> 9)) * 512 * 512;
  const int nl0 = n0 & 511;
  const int tid = threadIdx.x;
#pragma unroll
  for (int it = 0; it < 4; ++it) {
    const int idx = it * 256 + tid;
    const int r   = idx >> 4;
    const int c4  = (idx & 15) * 4;
    float4 v = *(const float4*)&I[(size_t)(n0 + r) * 512 + d0 + c4];
    short4v o;
    __hip_bfloat16* ob = (__hip_bfloat16*)&o;
    ob[0] = __float2bfloat16(v.x); ob[1] = __float2bfloat16(v.y);
    ob[2] = __float2bfloat16(v.z); ob[3] = __float2bfloat16(v.w);
    t[r][c4]     = ob[0]; t[r][c4 + 1] = ob[1];
    t[r][c4 + 2] = ob[2]; t[r][c4 + 3] = ob[3];
    *(short4v*)&XB[(size_t)(n0 + r) * 512 + d0 + c4] = o;
  }
  __syncthreads();
#pragma unroll
  for (int it = 0; it < 4; ++it) {
    const int idx = it * 256 + tid;
    const int dr  = idx >> 4;
    const int n4  = (idx & 15) * 4;
    short4v o;
    __hip_bfloat16* ob = (__hip_bfloat16*)&o;
#pragma unroll
    for (int j = 0; j < 4; j++) ob[j] = t[n4 + j][dr];
    *(short4v*)&XO[(size_t)(d0 + dr) * 512 + nl0 + n4] = o;
  }
}

// AT[b][i] = bf16(GELU(sum_kc part[(b*8+kc)][i]))
__global__ __launch_bounds__(256)
void reduce_gelu_bf16(const __hip_bfloat16* __restrict__ part,
                      __hip_bfloat16* __restrict__ AT) {
  const long o = ((long)blockIdx.x * 256 + threadIdx.x) * 8;
  const long b = o >> 18;
  const long i = o & 262143;
  float s[8] = {0.f, 0.f, 0.f, 0.f, 0.f, 0.f, 0.f, 0.f};
#pragma unroll
  for (int kc = 0; kc < 8; kc++) {
    short8 v = *(const short8*)(part + (((b << 3) + kc) << 18) + i);
#pragma unroll
    for (int j = 0; j < 8; j++) s[j] += __bfloat162float(((const __hip_bfloat16*)&v)[j]);
  }
  short8 o8;
#pragma unroll
  for (int j = 0; j < 8; j++)
    ((__hip_bfloat16*)&o8)[j] = __float2bfloat16(gelu_fast(s[j]));
  *(short8*)(AT + o) = o8;
}

extern "C" void kernel_launch(void* const* d_in, const int* in_sizes, int n_in,
                              void* d_out, int out_size, void* d_ws, size_t ws_size,
                              hipStream_t stream) {
  const float* X   = (const float*)d_in[0];
  const float* W1a = (const float*)d_in[1];
  const float* b1a = (const float*)d_in[2];
  const float* W1b = (const float*)d_in[3];
  const float* b1b = (const float*)d_in[4];
  const float* W2a = (const float*)d_in[5];
  const float* b2a = (const float*)d_in[6];
  const float* W2b = (const float*)d_in[7];
  const float* b2b = (const float*)d_in[8];
  float* Y = (float*)d_out;

  char* ws = (char*)d_ws;
  const size_t SZ = 33554432;  // 32768*512*2 B
  __hip_bfloat16* Xb   = (__hip_bfloat16*)(ws);                 // [8,4096,512]; later P partials [64][512][512]
  __hip_bfloat16* H    = (__hip_bfloat16*)(ws + SZ);            // [32768,512] (H1, then H2)
  __hip_bfloat16* W1T  = (__hip_bfloat16*)(ws + 2 * SZ);        // [8][8][512][512]; later W2m
  __hip_bfloat16* XT   = (__hip_bfloat16*)(ws + 3 * SZ);        // [8][8][512][512]
  __hip_bfloat16* AT   = (__hip_bfloat16*)(ws + 4 * SZ);        // [8][512][512]
  __hip_bfloat16* Wb   = (__hip_bfloat16*)(ws + 4 * SZ + 4194304);
  __hip_bfloat16* W1ab = Wb;
  __hip_bfloat16* W1bb = Wb + 262144;
  __hip_bfloat16* W2ab = Wb + 2 * 262144;
  __hip_bfloat16* W2bb = Wb + 3 * 262144;

  dim3 blk(256), blk512(512);

  // 0) conversions; X also emits chunked XT
  cvt_f32_bf16<<<128,  blk, 0, stream>>>(W1a, W1ab, 262144L);
  cvt_f32_bf16<<<128,  blk, 0, stream>>>(W1b, W1bb, 262144L);
  cvt_f32_bf16<<<128,  blk, 0, stream>>>(W2a, W2ab, 262144L);
  cvt_f32_bf16<<<128,  blk, 0, stream>>>(W2b, W2bb, 262144L);
  cvt_x_xt<<<dim3(8, 64, 8), blk, 0, stream>>>(X, Xb, XT);

  // 1) H1 = GELU(Xb @ W1a^T + b1a)
  g256_h1<<<dim3(2, 128, 1), blk512, 0, stream>>>(Xb, W1ab, b1a, H);
  // 2) W1Tc = H1 @ W1b^T + b1b (chunk-transposed)
  g256_w1t<<<dim3(2, 128, 1), blk512, 0, stream>>>(H, W1bb, b1b, W1T);
  // 3) H2 = GELU(Xb @ W2a^T + b2a)
  g256_h2<<<dim3(2, 128, 1), blk512, 0, stream>>>(Xb, W2ab, b2a, H);
  // 4) P partials: part[z] = XTc[z] @ W1Tc[z]^T  (64 x 512^3)
  __hip_bfloat16* part = Xb;  // Xb dead
  g256_p<<<dim3(2, 2, 64), blk512, 0, stream>>>(XT, W1T, part);
  // 5) AT = GELU(sum_kc part)
  reduce_gelu_bf16<<<1024, blk, 0, stream>>>(part, AT);
  // 6) W2m = H2 @ W2b^T + b2b  (reuse W1T buffer)
  __hip_bfloat16* W2m = W1T;
  g256_w2<<<dim3(2, 128, 1), blk512, 0, stream>>>(H, W2bb, b2b, W2m);
  // 7) Y = W2m @ AT^T per batch -> fp32
  g256_y<<<dim3(2, 16, 8), blk512, 0, stream>>>(W2m, AT, Y);
}

// Round 10
// 273.208 us; speedup vs baseline: 1.2280x; 1.0011x over previous
//
#include <hip/hip_runtime.h>
#include <hip/hip_bf16.h>

typedef __attribute__((ext_vector_type(8))) short short8;
typedef __attribute__((ext_vector_type(4))) short short4v;
typedef __attribute__((ext_vector_type(4))) float floatx4;

__device__ __forceinline__ void gload_lds16(const void* g, void* l) {
  __builtin_amdgcn_global_load_lds(
      (const __attribute__((address_space(1))) void*)g,
      (__attribute__((address_space(3))) void*)l, 16, 0, 0);
}

// tanh-approx GELU: max |err| vs exact-erf ~3e-3 (fine vs threshold 142)
__device__ __forceinline__ float gelu_fast(float x) {
  float z = 1.5957691216f * (x + 0.044715f * x * x * x);
  return x / (1.0f + __expf(-z));
}

#define FENCE() asm volatile("" ::: "memory")

// ================= 256x256x(K=512) counted-vmcnt GEMM =================
// C[M,512] = epi(A[M,512] @ B[512,512]^T + bias); 512 thr (8 waves, 2x4),
// per-wave out 128x64, BK=64, dbuf LDS 128KB.
// T2 swizzle via pre-swizzled global source (linear LDS dest + XOR'd ds_read).
// T4 pipeline: tiles kt+1,kt+2 in flight; vmcnt(8) waits only the older tile.
// SWZ=1: chunked XCD (grid total must be 256). SWZ=2: P-grid (2,2,64).
template<bool GELU_OUT, bool HASBIAS, bool STORE_T, bool OUT_F32, int SWZ>
__device__ __forceinline__
void gemm256_body(const __hip_bfloat16* __restrict__ Ag,
                  const __hip_bfloat16* __restrict__ Bg,
                  const float* __restrict__ bias,
                  void* __restrict__ Cg,
                  long sA, long sB, long sC)
{
  int bx, by, bz;
  if (SWZ == 1) {
    const int gx = gridDim.x, gy = gridDim.y;
    const int f = blockIdx.x + gx * (blockIdx.y + gy * blockIdx.z);
    const int l = (f & 7) * 32 + (f >> 3);          // total == 256
    bx = l % gx;
    const int rr = l / gx;
    by = rr % gy;
    bz = rr / gy;
  } else {  // SWZ==2: grid (2,2,64); 4 tiles of chunk z co-scheduled on one XCD
    const int f = blockIdx.x + 2 * (blockIdx.y + 2 * blockIdx.z);
    const int x = f & 7, s = f >> 3;
    bz = x + 8 * (s >> 2);
    bx = s & 1;
    by = (s >> 1) & 1;
  }
  const long za = bz;
  const __hip_bfloat16* A = Ag + za * sA;
  const __hip_bfloat16* B = Bg + za * sB;

  __shared__ __align__(16) __hip_bfloat16 SB[2][2 * 256 * 64];  // [buf][As|Bs] 128KB

  const int tid  = threadIdx.x;
  const int lane = tid & 63;
  const int wid  = tid >> 6;   // 0..7
  const int wr   = wid >> 2;   // 0..1 (row half)
  const int wc   = wid & 3;    // 0..3 (col quarter)
  const int brow = by * 256;
  const int bcol = bx * 256;

  floatx4 acc[8][4];
#pragma unroll
  for (int i = 0; i < 8; i++)
#pragma unroll
    for (int j = 0; j < 4; j++) acc[i][j] = (floatx4){0.f, 0.f, 0.f, 0.f};

  // staging: 4 passes x 64 rows; row = r*64 + (tid>>3); linear LDS slot tid&7;
  // pre-swizzled global slot = (tid&7) ^ (row&7)
  const int srow  = tid >> 3;                       // 0..63
  const int skoff = (((tid & 7) ^ (srow & 7))) * 8; // element offset in row

  auto STAGE = [&](int buf, int kt) {
    const int k0 = kt * 64;
#pragma unroll
    for (int r = 0; r < 4; ++r) {
      gload_lds16(A + (size_t)(brow + r * 64 + srow) * 512 + k0 + skoff,
                  (void*)(&SB[buf][0] + r * 4096 + tid * 8));
      gload_lds16(B + (size_t)(bcol + r * 64 + srow) * 512 + k0 + skoff,
                  (void*)(&SB[buf][16384] + r * 4096 + tid * 8));
    }
  };

  // read-side swizzled slot (elems): logical kslot = kk*4+(lane>>4), row&7 == lane&7
  const int rs0 = (((lane >> 4)) ^ (lane & 7)) * 8;
  const int rs1 = ((4 + (lane >> 4)) ^ (lane & 7)) * 8;

  // prologue: tiles 0 and 1 in flight; wait only tile 0 (oldest 8)
  STAGE(0, 0);
  STAGE(1, 1);
  asm volatile("s_waitcnt vmcnt(8)" ::: "memory");
  __builtin_amdgcn_s_barrier();
  FENCE();

  for (int kt = 0; kt < 8; ++kt) {
    const int cur = kt & 1;
    const __hip_bfloat16* As = &SB[cur][0];
    const __hip_bfloat16* Bs = &SB[cur][16384];
    __builtin_amdgcn_s_setprio(1);
#pragma unroll
    for (int kk = 0; kk < 2; ++kk) {
      const int rs = kk ? rs1 : rs0;
      short8 a[8], b[4];
#pragma unroll
      for (int i = 0; i < 8; i++)
        a[i] = *(const short8*)(As + (wr * 128 + i * 16 + (lane & 15)) * 64 + rs);
#pragma unroll
      for (int j = 0; j < 4; j++)
        b[j] = *(const short8*)(Bs + (wc * 64 + j * 16 + (lane & 15)) * 64 + rs);
#pragma unroll
      for (int i = 0; i < 8; i++)
#pragma unroll
        for (int j = 0; j < 4; j++)
          acc[i][j] = __builtin_amdgcn_mfma_f32_16x16x32_bf16(a[i], b[j], acc[i][j], 0, 0, 0);
    }
    __builtin_amdgcn_s_setprio(0);

    if (kt < 7) {
      // all waves done reading SB[cur] before its refill is issued
      __builtin_amdgcn_s_barrier();
      FENCE();
      if (kt + 2 < 8) {
        STAGE(cur, kt + 2);                               // +8 newer loads
        asm volatile("s_waitcnt vmcnt(8)" ::: "memory");  // tile kt+1 landed
      } else {
        asm volatile("s_waitcnt vmcnt(0)" ::: "memory");  // last tile landed
      }
      __builtin_amdgcn_s_barrier();
      FENCE();
    }
  }

  // epilogue: C/D layout col=lane&15, row=(lane>>4)*4+reg
  if (STORE_T) {
    // chunked-transposed store [b][n>>9][p][n&511] via LDS transpose, 2 n-halves
    __syncthreads();                       // all waves done with SB
    __hip_bfloat16* tr = &SB[0][0];        // [256 p][132 n-half] = 67.6KB
    const int bb  = brow >> 12;
    const int nc  = (brow & 4095) >> 9;
    const int nlo = brow & 511;            // 0 or 256
#pragma unroll
    for (int h = 0; h < 2; ++h) {
      if (wr == h) {
#pragma unroll
        for (int i = 0; i < 8; i++) {
          const int nl = i * 16 + (lane >> 4) * 4;   // 0..124 within half
#pragma unroll
          for (int j = 0; j < 4; j++) {
            const int col = wc * 64 + j * 16 + (lane & 15);
            const float bv = HASBIAS ? bias[bcol + col] : 0.f;
            short4v w;
            __hip_bfloat16* wb = (__hip_bfloat16*)&w;
#pragma unroll
            for (int r = 0; r < 4; r++) {
              float v = acc[i][j][r] + bv;
              if (GELU_OUT) v = gelu_fast(v);
              wb[r] = __float2bfloat16(v);
            }
            *(short4v*)&tr[col * 132 + nl] = w;
          }
        }
      }
      __syncthreads();
      const int p   = tid >> 1;
      const int seg = (tid & 1) * 64;
      __hip_bfloat16* outp = (__hip_bfloat16*)Cg +
          ((size_t)(bb * 8 + nc) * 512 + bcol + p) * 512 + nlo + h * 128 + seg;
#pragma unroll
      for (int q = 0; q < 8; q++)
        *(short8*)(outp + q * 8) = *(const short8*)&tr[p * 132 + seg + q * 8];
      __syncthreads();
    }
  } else {
#pragma unroll
    for (int i = 0; i < 8; i++) {
      const int row0 = brow + wr * 128 + i * 16 + (lane >> 4) * 4;
#pragma unroll
      for (int j = 0; j < 4; j++) {
        const int col = bcol + wc * 64 + j * 16 + (lane & 15);
        const float bv = HASBIAS ? bias[col] : 0.f;
#pragma unroll
        for (int r = 0; r < 4; r++) {
          float v = acc[i][j][r] + bv;
          if (GELU_OUT) v = gelu_fast(v);
          if (OUT_F32)
            ((float*)Cg + za * sC)[(size_t)(row0 + r) * 512 + col] = v;
          else
            ((__hip_bfloat16*)Cg + za * sC)[(size_t)(row0 + r) * 512 + col] = __float2bfloat16(v);
        }
      }
    }
  }
}

// ---- named instantiations ----
__global__ __launch_bounds__(512, 2)
void g256_h1(const __hip_bfloat16* A, const __hip_bfloat16* B, const float* bias, void* C) {
  gemm256_body<true, true, false, false, 1>(A, B, bias, C, 0, 0, 0);
}
__global__ __launch_bounds__(512, 2)
void g256_w1t(const __hip_bfloat16* A, const __hip_bfloat16* B, const float* bias, void* C) {
  gemm256_body<false, true, true, false, 1>(A, B, bias, C, 0, 0, 0);
}
__global__ __launch_bounds__(512, 2)
void g256_h2(const __hip_bfloat16* A, const __hip_bfloat16* B, const float* bias, void* C) {
  gemm256_body<true, true, false, false, 1>(A, B, bias, C, 0, 0, 0);
}
__global__ __launch_bounds__(512, 2)
void g256_w2(const __hip_bfloat16* A, const __hip_bfloat16* B, const float* bias, void* C) {
  gemm256_body<false, true, false, false, 1>(A, B, bias, C, 0, 0, 0);
}
__global__ __launch_bounds__(512, 2)
void g256_p(const __hip_bfloat16* A, const __hip_bfloat16* B, void* C) {
  gemm256_body<false, false, false, false, 2>(A, B, nullptr, C, 262144, 262144, 262144);
}
__global__ __launch_bounds__(512, 2)
void g256_y(const __hip_bfloat16* A, const __hip_bfloat16* B, void* C) {
  gemm256_body<false, false, false, true, 1>(A, B, nullptr, C,
                                             4096L * 512, 262144, 4096L * 512);
}

// fp32 -> bf16, 8 elements/thread
__global__ __launch_bounds__(256)
void cvt_f32_bf16(const float* __restrict__ in, __hip_bfloat16* __restrict__ out, long n) {
  long i = ((long)blockIdx.x * 256 + threadIdx.x) * 8;
  if (i >= n) return;
  float4 v0 = *(const float4*)(in + i);
  float4 v1 = *(const float4*)(in + i + 4);
  short8 o;
  __hip_bfloat16* ob = (__hip_bfloat16*)&o;
  ob[0] = __float2bfloat16(v0.x); ob[1] = __float2bfloat16(v0.y);
  ob[2] = __float2bfloat16(v0.z); ob[3] = __float2bfloat16(v0.w);
  ob[4] = __float2bfloat16(v1.x); ob[5] = __float2bfloat16(v1.y);
  ob[6] = __float2bfloat16(v1.z); ob[7] = __float2bfloat16(v1.w);
  *(short8*)(out + i) = o;
}

// X fp32 [B][4096][512] -> Xb bf16 + XTc bf16 [B][8][512][512]
__global__ __launch_bounds__(256)
void cvt_x_xt(const float* __restrict__ X,
              __hip_bfloat16* __restrict__ Xb,
              __hip_bfloat16* __restrict__ XT)
{
  __shared__ __hip_bfloat16 t[64][66];
  const int b  = blockIdx.z;
  const int n0 = blockIdx.y * 64;
  const int d0 = blockIdx.x * 64;
  const float* I = X + (size_t)b * 4096 * 512;
  __hip_bfloat16* XB = Xb + (size_t)b * 4096 * 512;
  __hip_bfloat16* XO = XT + ((size_t)b * 8 + (n0 >> 9)) * 512 * 512;
  const int nl0 = n0 & 511;
  const int tid = threadIdx.x;
#pragma unroll
  for (int it = 0; it < 4; ++it) {
    const int idx = it * 256 + tid;
    const int r   = idx >> 4;
    const int c4  = (idx & 15) * 4;
    float4 v = *(const float4*)&I[(size_t)(n0 + r) * 512 + d0 + c4];
    short4v o;
    __hip_bfloat16* ob = (__hip_bfloat16*)&o;
    ob[0] = __float2bfloat16(v.x); ob[1] = __float2bfloat16(v.y);
    ob[2] = __float2bfloat16(v.z); ob[3] = __float2bfloat16(v.w);
    t[r][c4]     = ob[0]; t[r][c4 + 1] = ob[1];
    t[r][c4 + 2] = ob[2]; t[r][c4 + 3] = ob[3];
    *(short4v*)&XB[(size_t)(n0 + r) * 512 + d0 + c4] = o;
  }
  __syncthreads();
#pragma unroll
  for (int it = 0; it < 4; ++it) {
    const int idx = it * 256 + tid;
    const int dr  = idx >> 4;
    const int n4  = (idx & 15) * 4;
    short4v o;
    __hip_bfloat16* ob = (__hip_bfloat16*)&o;
#pragma unroll
    for (int j = 0; j < 4; j++) ob[j] = t[n4 + j][dr];
    *(short4v*)&XO[(size_t)(d0 + dr) * 512 + nl0 + n4] = o;
  }
}

// AT[b][i] = bf16(GELU(sum_kc part[(b*8+kc)][i]))
__global__ __launch_bounds__(256)
void reduce_gelu_bf16(const __hip_bfloat16* __restrict__ part,
                      __hip_bfloat16* __restrict__ AT) {
  const long o = ((long)blockIdx.x * 256 + threadIdx.x) * 8;
  const long b = o >> 18;
  const long i = o & 262143;
  float s[8] = {0.f, 0.f, 0.f, 0.f, 0.f, 0.f, 0.f, 0.f};
#pragma unroll
  for (int kc = 0; kc < 8; kc++) {
    short8 v = *(const short8*)(part + (((b << 3) + kc) << 18) + i);
#pragma unroll
    for (int j = 0; j < 8; j++) s[j] += __bfloat162float(((const __hip_bfloat16*)&v)[j]);
  }
  short8 o8;
#pragma unroll
  for (int j = 0; j < 8; j++)
    ((__hip_bfloat16*)&o8)[j] = __float2bfloat16(gelu_fast(s[j]));
  *(short8*)(AT + o) = o8;
}

extern "C" void kernel_launch(void* const* d_in, const int* in_sizes, int n_in,
                              void* d_out, int out_size, void* d_ws, size_t ws_size,
                              hipStream_t stream) {
  const float* X   = (const float*)d_in[0];
  const float* W1a = (const float*)d_in[1];
  const float* b1a = (const float*)d_in[2];
  const float* W1b = (const float*)d_in[3];
  const float* b1b = (const float*)d_in[4];
  const float* W2a = (const float*)d_in[5];
  const float* b2a = (const float*)d_in[6];
  const float* W2b = (const float*)d_in[7];
  const float* b2b = (const float*)d_in[8];
  float* Y = (float*)d_out;

  char* ws = (char*)d_ws;
  const size_t SZ = 33554432;  // 32768*512*2 B
  __hip_bfloat16* Xb   = (__hip_bfloat16*)(ws);                 // [8,4096,512]; later P partials
  __hip_bfloat16* H    = (__hip_bfloat16*)(ws + SZ);            // [32768,512] (H1, then H2)
  __hip_bfloat16* W1T  = (__hip_bfloat16*)(ws + 2 * SZ);        // [8][8][512][512]; later W2m
  __hip_bfloat16* XT   = (__hip_bfloat16*)(ws + 3 * SZ);        // [8][8][512][512]
  __hip_bfloat16* AT   = (__hip_bfloat16*)(ws + 4 * SZ);        // [8][512][512]
  __hip_bfloat16* Wb   = (__hip_bfloat16*)(ws + 4 * SZ + 4194304);
  __hip_bfloat16* W1ab = Wb;
  __hip_bfloat16* W1bb = Wb + 262144;
  __hip_bfloat16* W2ab = Wb + 2 * 262144;
  __hip_bfloat16* W2bb = Wb + 3 * 262144;

  dim3 blk(256), blk512(512);

  // 0) conversions; X also emits chunked XT
  cvt_f32_bf16<<<128,  blk, 0, stream>>>(W1a, W1ab, 262144L);
  cvt_f32_bf16<<<128,  blk, 0, stream>>>(W1b, W1bb, 262144L);
  cvt_f32_bf16<<<128,  blk, 0, stream>>>(W2a, W2ab, 262144L);
  cvt_f32_bf16<<<128,  blk, 0, stream>>>(W2b, W2bb, 262144L);
  cvt_x_xt<<<dim3(8, 64, 8), blk, 0, stream>>>(X, Xb, XT);

  // 1) H1 = GELU(Xb @ W1a^T + b1a)
  g256_h1<<<dim3(2, 128, 1), blk512, 0, stream>>>(Xb, W1ab, b1a, H);
  // 2) W1Tc = H1 @ W1b^T + b1b (chunk-transposed)
  g256_w1t<<<dim3(2, 128, 1), blk512, 0, stream>>>(H, W1bb, b1b, W1T);
  // 3) H2 = GELU(Xb @ W2a^T + b2a)
  g256_h2<<<dim3(2, 128, 1), blk512, 0, stream>>>(Xb, W2ab, b2a, H);
  // 4) P partials: part[z] = XTc[z] @ W1Tc[z]^T  (64 x 512^3)
  __hip_bfloat16* part = Xb;  // Xb dead
  g256_p<<<dim3(2, 2, 64), blk512, 0, stream>>>(XT, W1T, part);
  // 5) AT = GELU(sum_kc part)
  reduce_gelu_bf16<<<1024, blk, 0, stream>>>(part, AT);
  // 6) W2m = H2 @ W2b^T + b2b  (reuse W1T buffer)
  __hip_bfloat16* W2m = W1T;
  g256_w2<<<dim3(2, 128, 1), blk512, 0, stream>>>(H, W2bb, b2b, W2m);
  // 7) Y = W2m @ AT^T per batch -> fp32
  g256_y<<<dim3(2, 16, 8), blk512, 0, stream>>>(W2m, AT, Y);
}

// Round 11
// 246.022 us; speedup vs baseline: 1.3637x; 1.1105x over previous
//
#include <hip/hip_runtime.h>
#include <hip/hip_bf16.h>

typedef __attribute__((ext_vector_type(8))) short short8;
typedef __attribute__((ext_vector_type(4))) short short4v;
typedef __attribute__((ext_vector_type(4))) float floatx4;

__device__ __forceinline__ void gload_lds16(const void* g, void* l) {
  __builtin_amdgcn_global_load_lds(
      (const __attribute__((address_space(1))) void*)g,
      (__attribute__((address_space(3))) void*)l, 16, 0, 0);
}

// tanh-approx GELU via sigmoid; rcp instead of precise div (bf16-accurate)
__device__ __forceinline__ float gelu_fast(float x) {
  float z = 1.5957691216f * (x + 0.044715f * x * x * x);
  float e = __expf(-z);
  return x * __builtin_amdgcn_rcpf(1.0f + e);
}

#define FENCE() asm volatile("" ::: "memory")

// ================= 256x256x(K=512) counted-vmcnt GEMM =================
// C[M,512] = epi(A[M,512] @ B[512,512]^T + bias); 512 thr (8 waves, 2x4),
// per-wave out 128x64, BK=64, dbuf LDS 128KB.
// T2 swizzle via pre-swizzled global source (linear LDS dest + XOR'd ds_read).
// T4 pipeline: tiles kt+1,kt+2 in flight; vmcnt(8) waits only the older tile.
// SWZ=1: chunked XCD (grid total must be 256). SWZ=2: P-grid (2,2,64).
template<bool GELU_OUT, bool HASBIAS, bool STORE_T, bool OUT_F32, int SWZ>
__device__ __forceinline__
void gemm256_body(const __hip_bfloat16* __restrict__ Ag,
                  const __hip_bfloat16* __restrict__ Bg,
                  const float* __restrict__ bias,
                  void* __restrict__ Cg,
                  long sA, long sB, long sC)
{
  int bx, by, bz;
  if (SWZ == 1) {
    const int gx = gridDim.x, gy = gridDim.y;
    const int f = blockIdx.x + gx * (blockIdx.y + gy * blockIdx.z);
    const int l = (f & 7) * 32 + (f >> 3);          // total == 256
    bx = l % gx;
    const int rr = l / gx;
    by = rr % gy;
    bz = rr / gy;
  } else {  // SWZ==2: grid (2,2,64); 4 tiles of chunk z co-scheduled on one XCD
    const int f = blockIdx.x + 2 * (blockIdx.y + 2 * blockIdx.z);
    const int x = f & 7, s = f >> 3;
    bz = x + 8 * (s >> 2);
    bx = s & 1;
    by = (s >> 1) & 1;
  }
  const long za = bz;
  const __hip_bfloat16* A = Ag + za * sA;
  const __hip_bfloat16* B = Bg + za * sB;

  __shared__ __align__(16) __hip_bfloat16 SB[2][2 * 256 * 64];  // [buf][As|Bs] 128KB

  const int tid  = threadIdx.x;
  const int lane = tid & 63;
  const int wid  = tid >> 6;   // 0..7
  const int wr   = wid >> 2;   // 0..1 (row half)
  const int wc   = wid & 3;    // 0..3 (col quarter)
  const int brow = by * 256;
  const int bcol = bx * 256;

  floatx4 acc[8][4];
#pragma unroll
  for (int i = 0; i < 8; i++)
#pragma unroll
    for (int j = 0; j < 4; j++) acc[i][j] = (floatx4){0.f, 0.f, 0.f, 0.f};

  // staging: 4 passes x 64 rows; row = r*64 + (tid>>3); linear LDS slot tid&7;
  // pre-swizzled global slot = (tid&7) ^ (row&7)
  const int srow  = tid >> 3;                       // 0..63
  const int skoff = (((tid & 7) ^ (srow & 7))) * 8; // element offset in row

  auto STAGE = [&](int buf, int kt) {
    const int k0 = kt * 64;
#pragma unroll
    for (int r = 0; r < 4; ++r) {
      gload_lds16(A + (size_t)(brow + r * 64 + srow) * 512 + k0 + skoff,
                  (void*)(&SB[buf][0] + r * 4096 + tid * 8));
      gload_lds16(B + (size_t)(bcol + r * 64 + srow) * 512 + k0 + skoff,
                  (void*)(&SB[buf][16384] + r * 4096 + tid * 8));
    }
  };

  // read-side swizzled slot (elems): logical kslot = kk*4+(lane>>4), row&7 == lane&7
  const int rs0 = (((lane >> 4)) ^ (lane & 7)) * 8;
  const int rs1 = ((4 + (lane >> 4)) ^ (lane & 7)) * 8;

  // prologue: tiles 0 and 1 in flight; wait only tile 0 (oldest 8)
  STAGE(0, 0);
  STAGE(1, 1);
  asm volatile("s_waitcnt vmcnt(8)" ::: "memory");
  __builtin_amdgcn_s_barrier();
  FENCE();

  for (int kt = 0; kt < 8; ++kt) {
    const int cur = kt & 1;
    const __hip_bfloat16* As = &SB[cur][0];
    const __hip_bfloat16* Bs = &SB[cur][16384];
    __builtin_amdgcn_s_setprio(1);
#pragma unroll
    for (int kk = 0; kk < 2; ++kk) {
      const int rs = kk ? rs1 : rs0;
      short8 a[8], b[4];
#pragma unroll
      for (int i = 0; i < 8; i++)
        a[i] = *(const short8*)(As + (wr * 128 + i * 16 + (lane & 15)) * 64 + rs);
#pragma unroll
      for (int j = 0; j < 4; j++)
        b[j] = *(const short8*)(Bs + (wc * 64 + j * 16 + (lane & 15)) * 64 + rs);
#pragma unroll
      for (int i = 0; i < 8; i++)
#pragma unroll
        for (int j = 0; j < 4; j++)
          acc[i][j] = __builtin_amdgcn_mfma_f32_16x16x32_bf16(a[i], b[j], acc[i][j], 0, 0, 0);
    }
    __builtin_amdgcn_s_setprio(0);

    if (kt < 7) {
      // all waves done reading SB[cur] before its refill is issued
      __builtin_amdgcn_s_barrier();
      FENCE();
      if (kt + 2 < 8) {
        STAGE(cur, kt + 2);                               // +8 newer loads
        asm volatile("s_waitcnt vmcnt(8)" ::: "memory");  // tile kt+1 landed
      } else {
        asm volatile("s_waitcnt vmcnt(0)" ::: "memory");  // last tile landed
      }
      __builtin_amdgcn_s_barrier();
      FENCE();
    }
  }

  // epilogue: C/D layout col=lane&15, row=(lane>>4)*4+reg
  if (STORE_T) {
    // chunked-transposed store [b][n>>9][p][n&511] via LDS transpose, 2 n-halves
    __syncthreads();                       // all waves done with SB
    __hip_bfloat16* tr = &SB[0][0];        // [256 p][132 n-half] = 67.6KB
    const int bb  = brow >> 12;
    const int nc  = (brow & 4095) >> 9;
    const int nlo = brow & 511;            // 0 or 256
#pragma unroll
    for (int h = 0; h < 2; ++h) {
      if (wr == h) {
#pragma unroll
        for (int i = 0; i < 8; i++) {
          const int nl = i * 16 + (lane >> 4) * 4;   // 0..124 within half
#pragma unroll
          for (int j = 0; j < 4; j++) {
            const int col = wc * 64 + j * 16 + (lane & 15);
            const float bv = HASBIAS ? bias[bcol + col] : 0.f;
            short4v w;
            __hip_bfloat16* wb = (__hip_bfloat16*)&w;
#pragma unroll
            for (int r = 0; r < 4; r++) {
              float v = acc[i][j][r] + bv;
              if (GELU_OUT) v = gelu_fast(v);
              wb[r] = __float2bfloat16(v);
            }
            *(short4v*)&tr[col * 132 + nl] = w;
          }
        }
      }
      __syncthreads();
      const int p   = tid >> 1;
      const int seg = (tid & 1) * 64;
      __hip_bfloat16* outp = (__hip_bfloat16*)Cg +
          ((size_t)(bb * 8 + nc) * 512 + bcol + p) * 512 + nlo + h * 128 + seg;
#pragma unroll
      for (int q = 0; q < 8; q++)
        *(short8*)(outp + q * 8) = *(const short8*)&tr[p * 132 + seg + q * 8];
      __syncthreads();
    }
  } else {
#pragma unroll
    for (int i = 0; i < 8; i++) {
      const int row0 = brow + wr * 128 + i * 16 + (lane >> 4) * 4;
#pragma unroll
      for (int j = 0; j < 4; j++) {
        const int col = bcol + wc * 64 + j * 16 + (lane & 15);
        const float bv = HASBIAS ? bias[col] : 0.f;
#pragma unroll
        for (int r = 0; r < 4; r++) {
          float v = acc[i][j][r] + bv;
          if (GELU_OUT) v = gelu_fast(v);
          if (OUT_F32)
            ((float*)Cg + za * sC)[(size_t)(row0 + r) * 512 + col] = v;
          else
            ((__hip_bfloat16*)Cg + za * sC)[(size_t)(row0 + r) * 512 + col] = __float2bfloat16(v);
        }
      }
    }
  }
}

// ---- named instantiations ----
// h1/h2 now GELU-free: byte-identical template config to w2 (the fast one).
__global__ __launch_bounds__(512, 2)
void g256_h1(const __hip_bfloat16* A, const __hip_bfloat16* B, const float* bias, void* C) {
  gemm256_body<false, true, false, false, 1>(A, B, bias, C, 0, 0, 0);
}
__global__ __launch_bounds__(512, 2)
void g256_w1t(const __hip_bfloat16* A, const __hip_bfloat16* B, const float* bias, void* C) {
  gemm256_body<false, true, true, false, 1>(A, B, bias, C, 0, 0, 0);
}
__global__ __launch_bounds__(512, 2)
void g256_h2(const __hip_bfloat16* A, const __hip_bfloat16* B, const float* bias, void* C) {
  gemm256_body<false, true, false, false, 1>(A, B, bias, C, 0, 0, 0);
}
__global__ __launch_bounds__(512, 2)
void g256_w2(const __hip_bfloat16* A, const __hip_bfloat16* B, const float* bias, void* C) {
  gemm256_body<false, true, false, false, 1>(A, B, bias, C, 0, 0, 0);
}
__global__ __launch_bounds__(512, 2)
void g256_p(const __hip_bfloat16* A, const __hip_bfloat16* B, void* C) {
  gemm256_body<false, false, false, false, 2>(A, B, nullptr, C, 262144, 262144, 262144);
}
__global__ __launch_bounds__(512, 2)
void g256_y(const __hip_bfloat16* A, const __hip_bfloat16* B, void* C) {
  gemm256_body<false, false, false, true, 1>(A, B, nullptr, C,
                                             4096L * 512, 262144, 4096L * 512);
}

// in-place GELU over bf16 buffer, 8 elems/thread
__global__ __launch_bounds__(256)
void gelu_inplace(__hip_bfloat16* __restrict__ H, long n) {
  long i = ((long)blockIdx.x * 256 + threadIdx.x) * 8;
  if (i >= n) return;
  short8 v = *(const short8*)(H + i);
  short8 o;
#pragma unroll
  for (int j = 0; j < 8; j++) {
    float x = __bfloat162float(((const __hip_bfloat16*)&v)[j]);
    ((__hip_bfloat16*)&o)[j] = __float2bfloat16(gelu_fast(x));
  }
  *(short8*)(H + i) = o;
}

// fp32 -> bf16, 8 elements/thread
__global__ __launch_bounds__(256)
void cvt_f32_bf16(const float* __restrict__ in, __hip_bfloat16* __restrict__ out, long n) {
  long i = ((long)blockIdx.x * 256 + threadIdx.x) * 8;
  if (i >= n) return;
  float4 v0 = *(const float4*)(in + i);
  float4 v1 = *(const float4*)(in + i + 4);
  short8 o;
  __hip_bfloat16* ob = (__hip_bfloat16*)&o;
  ob[0] = __float2bfloat16(v0.x); ob[1] = __float2bfloat16(v0.y);
  ob[2] = __float2bfloat16(v0.z); ob[3] = __float2bfloat16(v0.w);
  ob[4] = __float2bfloat16(v1.x); ob[5] = __float2bfloat16(v1.y);
  ob[6] = __float2bfloat16(v1.z); ob[7] = __float2bfloat16(v1.w);
  *(short8*)(out + i) = o;
}

// X fp32 [B][4096][512] -> Xb bf16 + XTc bf16 [B][8][512][512]
__global__ __launch_bounds__(256)
void cvt_x_xt(const float* __restrict__ X,
              __hip_bfloat16* __restrict__ Xb,
              __hip_bfloat16* __restrict__ XT)
{
  __shared__ __hip_bfloat16 t[64][66];
  const int b  = blockIdx.z;
  const int n0 = blockIdx.y * 64;
  const int d0 = blockIdx.x * 64;
  const float* I = X + (size_t)b * 4096 * 512;
  __hip_bfloat16* XB = Xb + (size_t)b * 4096 * 512;
  __hip_bfloat16* XO = XT + ((size_t)b * 8 + (n0 >> 9)) * 512 * 512;
  const int nl0 = n0 & 511;
  const int tid = threadIdx.x;
#pragma unroll
  for (int it = 0; it < 4; ++it) {
    const int idx = it * 256 + tid;
    const int r   = idx >> 4;
    const int c4  = (idx & 15) * 4;
    float4 v = *(const float4*)&I[(size_t)(n0 + r) * 512 + d0 + c4];
    short4v o;
    __hip_bfloat16* ob = (__hip_bfloat16*)&o;
    ob[0] = __float2bfloat16(v.x); ob[1] = __float2bfloat16(v.y);
    ob[2] = __float2bfloat16(v.z); ob[3] = __float2bfloat16(v.w);
    t[r][c4]     = ob[0]; t[r][c4 + 1] = ob[1];
    t[r][c4 + 2] = ob[2]; t[r][c4 + 3] = ob[3];
    *(short4v*)&XB[(size_t)(n0 + r) * 512 + d0 + c4] = o;
  }
  __syncthreads();
#pragma unroll
  for (int it = 0; it < 4; ++it) {
    const int idx = it * 256 + tid;
    const int dr  = idx >> 4;
    const int n4  = (idx & 15) * 4;
    short4v o;
    __hip_bfloat16* ob = (__hip_bfloat16*)&o;
#pragma unroll
    for (int j = 0; j < 4; j++) ob[j] = t[n4 + j][dr];
    *(short4v*)&XO[(size_t)(d0 + dr) * 512 + nl0 + n4] = o;
  }
}

// AT[b][i] = bf16(GELU(sum_kc part[(b*8+kc)][i]))
__global__ __launch_bounds__(256)
void reduce_gelu_bf16(const __hip_bfloat16* __restrict__ part,
                      __hip_bfloat16* __restrict__ AT) {
  const long o = ((long)blockIdx.x * 256 + threadIdx.x) * 8;
  const long b = o >> 18;
  const long i = o & 262143;
  float s[8] = {0.f, 0.f, 0.f, 0.f, 0.f, 0.f, 0.f, 0.f};
#pragma unroll
  for (int kc = 0; kc < 8; kc++) {
    short8 v = *(const short8*)(part + (((b << 3) + kc) << 18) + i);
#pragma unroll
    for (int j = 0; j < 8; j++) s[j] += __bfloat162float(((const __hip_bfloat16*)&v)[j]);
  }
  short8 o8;
#pragma unroll
  for (int j = 0; j < 8; j++)
    ((__hip_bfloat16*)&o8)[j] = __float2bfloat16(gelu_fast(s[j]));
  *(short8*)(AT + o) = o8;
}

extern "C" void kernel_launch(void* const* d_in, const int* in_sizes, int n_in,
                              void* d_out, int out_size, void* d_ws, size_t ws_size,
                              hipStream_t stream) {
  const float* X   = (const float*)d_in[0];
  const float* W1a = (const float*)d_in[1];
  const float* b1a = (const float*)d_in[2];
  const float* W1b = (const float*)d_in[3];
  const float* b1b = (const float*)d_in[4];
  const float* W2a = (const float*)d_in[5];
  const float* b2a = (const float*)d_in[6];
  const float* W2b = (const float*)d_in[7];
  const float* b2b = (const float*)d_in[8];
  float* Y = (float*)d_out;

  char* ws = (char*)d_ws;
  const size_t SZ = 33554432;  // 32768*512*2 B
  __hip_bfloat16* Xb   = (__hip_bfloat16*)(ws);                 // [8,4096,512]; later P partials
  __hip_bfloat16* H    = (__hip_bfloat16*)(ws + SZ);            // [32768,512] (H1, then H2)
  __hip_bfloat16* W1T  = (__hip_bfloat16*)(ws + 2 * SZ);        // [8][8][512][512]; later W2m
  __hip_bfloat16* XT   = (__hip_bfloat16*)(ws + 3 * SZ);        // [8][8][512][512]
  __hip_bfloat16* AT   = (__hip_bfloat16*)(ws + 4 * SZ);        // [8][512][512]
  __hip_bfloat16* Wb   = (__hip_bfloat16*)(ws + 4 * SZ + 4194304);
  __hip_bfloat16* W1ab = Wb;
  __hip_bfloat16* W1bb = Wb + 262144;
  __hip_bfloat16* W2ab = Wb + 2 * 262144;
  __hip_bfloat16* W2bb = Wb + 3 * 262144;

  dim3 blk(256), blk512(512);

  // 0) conversions; X also emits chunked XT
  cvt_f32_bf16<<<128,  blk, 0, stream>>>(W1a, W1ab, 262144L);
  cvt_f32_bf16<<<128,  blk, 0, stream>>>(W1b, W1bb, 262144L);
  cvt_f32_bf16<<<128,  blk, 0, stream>>>(W2a, W2ab, 262144L);
  cvt_f32_bf16<<<128,  blk, 0, stream>>>(W2b, W2bb, 262144L);
  cvt_x_xt<<<dim3(8, 64, 8), blk, 0, stream>>>(X, Xb, XT);

  // 1) H1pre = Xb @ W1a^T + b1a  (no GELU in epilogue)
  g256_h1<<<dim3(2, 128, 1), blk512, 0, stream>>>(Xb, W1ab, b1a, H);
  // 1b) H1 = GELU(H1pre) in-place
  gelu_inplace<<<8192, blk, 0, stream>>>(H, 16777216L);
  // 2) W1Tc = H1 @ W1b^T + b1b (chunk-transposed)
  g256_w1t<<<dim3(2, 128, 1), blk512, 0, stream>>>(H, W1bb, b1b, W1T);
  // 3) H2pre = Xb @ W2a^T + b2a
  g256_h2<<<dim3(2, 128, 1), blk512, 0, stream>>>(Xb, W2ab, b2a, H);
  // 3b) H2 = GELU(H2pre) in-place
  gelu_inplace<<<8192, blk, 0, stream>>>(H, 16777216L);
  // 4) P partials: part[z] = XTc[z] @ W1Tc[z]^T  (64 x 512^3)
  __hip_bfloat16* part = Xb;  // Xb dead
  g256_p<<<dim3(2, 2, 64), blk512, 0, stream>>>(XT, W1T, part);
  // 5) AT = GELU(sum_kc part)
  reduce_gelu_bf16<<<1024, blk, 0, stream>>>(part, AT);
  // 6) W2m = H2 @ W2b^T + b2b  (reuse W1T buffer)
  __hip_bfloat16* W2m = W1T;
  g256_w2<<<dim3(2, 128, 1), blk512, 0, stream>>>(H, W2bb, b2b, W2m);
  // 7) Y = W2m @ AT^T per batch -> fp32
  g256_y<<<dim3(2, 16, 8), blk512, 0, stream>>>(W2m, AT, Y);
}